// Round 10
// baseline (19596.773 us; speedup 1.0000x reference)
//
#include <hip/hip_runtime.h>
#include <stdint.h>

#define NB 128      // batch
#define NH 512      // hidden
#define NE 128      // embedding dim
#define NVOC 32000  // vocab
#define NNV 196     // visual tokens
#define NDV 256     // visual dim
#define NSTEPS 32
#define SORTSTRIDE 32768
#define VTOK (NB * NNV)   // 25088 visual token rows

// offs layout: [w][d] with padded stride 257 (257 % 32 == 1 -> bank = (w+d)%32).
#define OFFS_STRIDE 257
#define OFFS_SIZE (16 * OFFS_STRIDE)   // 4112 words

// ---------------- Threefry-2x32 (20 rounds), exact JAX semantics --------------
static __device__ __forceinline__ uint32_t rotl32(uint32_t x, int r){
  return (x << r) | (x >> (32 - r));
}

static __device__ __forceinline__ void threefry2x32(uint32_t k0, uint32_t k1,
    uint32_t x0, uint32_t x1, uint32_t &o0, uint32_t &o1){
  uint32_t k2 = k0 ^ k1 ^ 0x1BD11BDAu;
  x0 += k0; x1 += k1;
#define TF_RND(r) { x0 += x1; x1 = rotl32(x1,(r)); x1 ^= x0; }
  TF_RND(13) TF_RND(15) TF_RND(26) TF_RND(6)
  x0 += k1; x1 += k2 + 1u;
  TF_RND(17) TF_RND(29) TF_RND(16) TF_RND(24)
  x0 += k2; x1 += k0 + 2u;
  TF_RND(13) TF_RND(15) TF_RND(26) TF_RND(6)
  x0 += k0; x1 += k1 + 3u;
  TF_RND(17) TF_RND(29) TF_RND(16) TF_RND(24)
  x0 += k1; x1 += k2 + 4u;
  TF_RND(13) TF_RND(15) TF_RND(26) TF_RND(6)
  x0 += k2; x1 += k0 + 5u;
#undef TF_RND
  o0 = x0; o1 = x1;
}

// ---------------- visual projection GEMM (tiled, coalesced) -------------------
__global__ __launch_bounds__(256) void k_visgemm(
    const float* __restrict__ vf,     // [VTOK][NDV]
    const float* __restrict__ vis_w,  // [NH][NDV]
    const float* __restrict__ vis_b,
    float* __restrict__ vp)           // [VTOK][NH] (raw, pre-LN)
{
  __shared__ float As[64][68];
  __shared__ float Ws[64][68];
  int tid = threadIdx.x;
  int tx = tid & 15;          // h sub-tile
  int ty = tid >> 4;          // token sub-tile
  int mb = blockIdx.x * 64;   // token base
  int hb = blockIdx.y * 64;   // hidden base
  int m_l = ty * 4, h_l = tx * 4;

  float acc[4][4];
  #pragma unroll
  for (int i = 0; i < 4; i++)
    #pragma unroll
    for (int j = 0; j < 4; j++) acc[i][j] = 0.f;

  for (int kc = 0; kc < NDV; kc += 64){
    __syncthreads();
    for (int q = tid; q < 1024; q += 256){
      int m = q >> 4, k4 = (q & 15) << 2;
      *(float4*)&As[m][k4] = *(const float4*)(vf + (size_t)(mb + m) * NDV + kc + k4);
    }
    for (int q = tid; q < 1024; q += 256){
      int h = q >> 4, k4 = (q & 15) << 2;
      *(float4*)&Ws[h][k4] = *(const float4*)(vis_w + (size_t)(hb + h) * NDV + kc + k4);
    }
    __syncthreads();
#define FMA4(i,j,av,wv) \
    acc[i][j] = fmaf(av.x, wv.x, acc[i][j]); \
    acc[i][j] = fmaf(av.y, wv.y, acc[i][j]); \
    acc[i][j] = fmaf(av.z, wv.z, acc[i][j]); \
    acc[i][j] = fmaf(av.w, wv.w, acc[i][j]);
    #pragma unroll 4
    for (int kk = 0; kk < 64; kk += 4){
      float4 a0 = *(const float4*)&As[m_l + 0][kk];
      float4 a1 = *(const float4*)&As[m_l + 1][kk];
      float4 a2 = *(const float4*)&As[m_l + 2][kk];
      float4 a3 = *(const float4*)&As[m_l + 3][kk];
      float4 w0 = *(const float4*)&Ws[h_l + 0][kk];
      float4 w1 = *(const float4*)&Ws[h_l + 1][kk];
      float4 w2 = *(const float4*)&Ws[h_l + 2][kk];
      float4 w3 = *(const float4*)&Ws[h_l + 3][kk];
      FMA4(0,0,a0,w0) FMA4(0,1,a0,w1) FMA4(0,2,a0,w2) FMA4(0,3,a0,w3)
      FMA4(1,0,a1,w0) FMA4(1,1,a1,w1) FMA4(1,2,a1,w2) FMA4(1,3,a1,w3)
      FMA4(2,0,a2,w0) FMA4(2,1,a2,w1) FMA4(2,2,a2,w2) FMA4(2,3,a2,w3)
      FMA4(3,0,a3,w0) FMA4(3,1,a3,w1) FMA4(3,2,a3,w2) FMA4(3,3,a3,w3)
    }
#undef FMA4
  }

  float4 bias = *(const float4*)(vis_b + hb + h_l);
  #pragma unroll
  for (int i = 0; i < 4; i++){
    float4 o;
    o.x = acc[i][0] + bias.x;
    o.y = acc[i][1] + bias.y;
    o.z = acc[i][2] + bias.z;
    o.w = acc[i][3] + bias.w;
    *(float4*)(vp + (size_t)(mb + m_l + i) * NH + hb + h_l) = o;
  }
}

// ---------------- LayerNorm over vp rows, in place ----------------------------
__global__ __launch_bounds__(256) void k_visln(
    const float* __restrict__ ln_g, const float* __restrict__ ln_b,
    float* __restrict__ vp)
{
  int bn = blockIdx.x;
  int tid = threadIdx.x;
  __shared__ float red[256];
  float* op = vp + (size_t)bn * NH;
  float out0 = op[tid];
  float out1 = op[tid + 256];
  red[tid] = out0 + out1; __syncthreads();
  for (int s = 128; s > 0; s >>= 1){ if (tid < s) red[tid] += red[tid + s]; __syncthreads(); }
  float mu = red[0] * (1.0f / (float)NH);
  __syncthreads();
  float d0 = out0 - mu, d1 = out1 - mu;
  red[tid] = d0*d0 + d1*d1; __syncthreads();
  for (int s = 128; s > 0; s >>= 1){ if (tid < s) red[tid] += red[tid + s]; __syncthreads(); }
  float var = red[0] * (1.0f / (float)NH);
  float r = 1.0f / sqrtf(var + 1e-5f);
  op[tid]       = d0 * r * ln_g[tid]       + ln_b[tid];
  op[tid + 256] = d1 * r * ln_g[tid + 256] + ln_b[tid + 256];
}

// ---------------- init hidden states ------------------------------------------
__global__ void k_init(const float* __restrict__ thought,
                       float* __restrict__ h0, float* __restrict__ c0,
                       float* __restrict__ h1, float* __restrict__ c1)
{
  int id = blockIdx.x * 256 + threadIdx.x;
  if (id >= NH * NB) return;
  int k = id >> 7;
  int b = id & 127;
  float v = thought[(size_t)b * NH + k];
  h0[id] = v; h1[id] = v; c0[id] = 0.f; c1[id] = 0.f;
}

// ---------------- fused LSTM layer (GEMM + cell) -------------------------------
template<int K1>
__global__ __launch_bounds__(256) void k_lstm(
    const float* __restrict__ wih, const float* __restrict__ whh,
    const float* __restrict__ bih, const float* __restrict__ bhh,
    const float* __restrict__ a1,
    const int*   __restrict__ toks, int step,
    const float* __restrict__ hprev, const float* __restrict__ cprev,
    float* __restrict__ hout, float* __restrict__ cout)
{
  __shared__ float As[64][64];
  __shared__ float Ws[4 * 16 * 68];
  __shared__ int tokl[64];
  int tid = threadIdx.x;
  int jl = tid & 15;
  int bg = tid >> 4;
  int jbase = blockIdx.x * 16;
  int j = jbase + jl;
  int bblk = blockIdx.y * 64;
  int bl = bg * 4;
  if (K1 == NE){
    if (tid < 64) tokl[tid] = (step == 0) ? 1 : toks[(size_t)(bblk + tid) * NSTEPS + step - 1];
  }
  __syncthreads();

  float acc[4][4];
  #pragma unroll
  for (int g = 0; g < 4; g++)
    #pragma unroll
    for (int e = 0; e < 4; e++) acc[g][e] = 0.f;

  for (int part = 0; part < 2; part++){
    const float* Wsrc = part ? whh : wih;
    const float* Asrc = part ? hprev : a1;
    const int K = part ? NH : K1;
    const bool gather = (!part) && (K1 == NE);
    for (int kc = 0; kc < K; kc += 64){
      __syncthreads();
      for (int q = tid; q < 1024; q += 256){
        int kk = q >> 4;
        int bb = (q & 15) << 2;
        float4 v;
        if (gather){
          v.x = Asrc[(size_t)tokl[bb+0] * NE + kc + kk];
          v.y = Asrc[(size_t)tokl[bb+1] * NE + kc + kk];
          v.z = Asrc[(size_t)tokl[bb+2] * NE + kc + kk];
          v.w = Asrc[(size_t)tokl[bb+3] * NE + kc + kk];
        } else {
          v = *(const float4*)(Asrc + (size_t)(kc + kk) * NB + bblk + bb);
        }
        *(float4*)&As[kk][bb] = v;
      }
      for (int q = tid; q < 1024; q += 256){
        int r = q >> 4;
        int f = q & 15;
        int g = r >> 4;
        int jj = r & 15;
        float4 w = *(const float4*)(Wsrc + (size_t)(g * NH + jbase + jj) * K + kc + f * 4);
        float* wd = &Ws[(g * 16 + jj) * 68 + f * 4];
        wd[0] = w.x; wd[1] = w.y; wd[2] = w.z; wd[3] = w.w;
      }
      __syncthreads();
      #pragma unroll 2
      for (int kk = 0; kk < 64; kk += 4){
        float4 a0 = *(const float4*)&As[kk + 0][bl];
        float4 a1v = *(const float4*)&As[kk + 1][bl];
        float4 a2 = *(const float4*)&As[kk + 2][bl];
        float4 a3 = *(const float4*)&As[kk + 3][bl];
        #pragma unroll
        for (int g = 0; g < 4; g++){
          float4 w = *(const float4*)&Ws[(g * 16 + jl) * 68 + kk];
          acc[g][0] = fmaf(a0.x, w.x, acc[g][0]);
          acc[g][1] = fmaf(a0.y, w.x, acc[g][1]);
          acc[g][2] = fmaf(a0.z, w.x, acc[g][2]);
          acc[g][3] = fmaf(a0.w, w.x, acc[g][3]);
          acc[g][0] = fmaf(a1v.x, w.y, acc[g][0]);
          acc[g][1] = fmaf(a1v.y, w.y, acc[g][1]);
          acc[g][2] = fmaf(a1v.z, w.y, acc[g][2]);
          acc[g][3] = fmaf(a1v.w, w.y, acc[g][3]);
          acc[g][0] = fmaf(a2.x, w.z, acc[g][0]);
          acc[g][1] = fmaf(a2.y, w.z, acc[g][1]);
          acc[g][2] = fmaf(a2.z, w.z, acc[g][2]);
          acc[g][3] = fmaf(a2.w, w.z, acc[g][3]);
          acc[g][0] = fmaf(a3.x, w.w, acc[g][0]);
          acc[g][1] = fmaf(a3.y, w.w, acc[g][1]);
          acc[g][2] = fmaf(a3.z, w.w, acc[g][2]);
          acc[g][3] = fmaf(a3.w, w.w, acc[g][3]);
        }
      }
    }
  }

  float bi[4];
  #pragma unroll
  for (int g = 0; g < 4; g++) bi[g] = bih[g * NH + j] + bhh[g * NH + j];
  int b0g = bblk + bl;
  float4 cp = *(const float4*)(cprev + (size_t)j * NB + b0g);
  float cpv[4] = {cp.x, cp.y, cp.z, cp.w};
  float hs[4], cs[4];
  #pragma unroll
  for (int e = 0; e < 4; e++){
    float zi = acc[0][e] + bi[0];
    float zf = acc[1][e] + bi[1];
    float zg = acc[2][e] + bi[2];
    float zo = acc[3][e] + bi[3];
    float si = 1.f / (1.f + expf(-zi));
    float sf = 1.f / (1.f + expf(-zf));
    float so = 1.f / (1.f + expf(-zo));
    float tg = tanhf(zg);
    float c2 = sf * cpv[e] + si * tg;
    cs[e] = c2;
    hs[e] = so * tanhf(c2);
  }
  *(float4*)(cout + (size_t)j * NB + b0g) = make_float4(cs[0], cs[1], cs[2], cs[3]);
  *(float4*)(hout + (size_t)j * NB + b0g) = make_float4(hs[0], hs[1], hs[2], hs[3]);
}

// ---------------- gate + visual attention --------------------------------------
__global__ __launch_bounds__(256) void k_gateattn(
    const float* __restrict__ h1t,
    const float* __restrict__ gw1, const float* __restrict__ gb1,
    const float* __restrict__ gw2, const float* __restrict__ gb2,
    const float* __restrict__ vp,
    float* __restrict__ o2t)
{
  int b = blockIdx.x;
  int tid = threadIdx.x;
  __shared__ float hsm[NH];
  __shared__ float tsm[NH];
  __shared__ float osm[NH];
  __shared__ float aw[NNV];
  __shared__ float red[256];
  for (int h = tid; h < NH; h += 256) hsm[h] = h1t[(size_t)h * NB + b];
  __syncthreads();
  for (int jj = tid; jj < NH; jj += 256){
    const float4* wr = (const float4*)(gw1 + (size_t)jj * NH);
    const float4* h4 = (const float4*)hsm;
    float acc = 0.f;
    #pragma unroll 4
    for (int k = 0; k < NH/4; k++){
      float4 w = wr[k]; float4 hh = h4[k];
      acc = fmaf(hh.x, w.x, acc);
      acc = fmaf(hh.y, w.y, acc);
      acc = fmaf(hh.z, w.z, acc);
      acc = fmaf(hh.w, w.w, acc);
    }
    tsm[jj] = tanhf(acc + gb1[jj]);
  }
  __syncthreads();
  float part = 0.f;
  for (int jj = tid; jj < NH; jj += 256) part = fmaf(tsm[jj], gw2[jj], part);
  red[tid] = part; __syncthreads();
  for (int s = 128; s > 0; s >>= 1){ if (tid < s) red[tid] += red[tid + s]; __syncthreads(); }
  float gate = 1.f / (1.f + expf(-(red[0] + gb2[0])));
  __syncthreads();
  for (int h = tid; h < NH; h += 256) osm[h] = hsm[h] * gate;
  __syncthreads();
  const float* vpb = vp + (size_t)b * NNV * NH;
  float sc = 0.f;
  if (tid < NNV){
    const float4* vr = (const float4*)(vpb + (size_t)tid * NH);
    const float4* o4 = (const float4*)osm;
    float accv = 0.f;
    #pragma unroll 4
    for (int k = 0; k < NH/4; k++){
      float4 v = vr[k]; float4 oo = o4[k];
      accv = fmaf(oo.x, v.x, accv);
      accv = fmaf(oo.y, v.y, accv);
      accv = fmaf(oo.z, v.z, accv);
      accv = fmaf(oo.w, v.w, accv);
    }
    sc = accv / 22.62741699796952f;   // scores / sqrt(512)
  }
  red[tid] = (tid < NNV) ? sc : -INFINITY;
  __syncthreads();
  for (int s = 128; s > 0; s >>= 1){ if (tid < s) red[tid] = fmaxf(red[tid], red[tid + s]); __syncthreads(); }
  float mx = red[0];
  __syncthreads();
  float ev = (tid < NNV) ? expf(sc - mx) : 0.f;
  red[tid] = ev; __syncthreads();
  for (int s = 128; s > 0; s >>= 1){ if (tid < s) red[tid] += red[tid + s]; __syncthreads(); }
  float zs = red[0];
  if (tid < NNV) aw[tid] = ev / zs;
  __syncthreads();
  for (int h = tid; h < NH; h += 256){
    float accv = 0.f;
    for (int n = 0; n < NNV; n++) accv = fmaf(aw[n], vpb[(size_t)n * NH + h], accv);
    o2t[(size_t)h * NB + b] = osm[h] + accv;
  }
}

// ---------------- logits GEMM + rep-penalty + temperature -----------------------
__global__ __launch_bounds__(256, 4) void k_logits(
    const float* __restrict__ o2t,     // [NH][NB]
    const float* __restrict__ outw,    // [NVOC][NH]
    const float* __restrict__ outb,
    const int* __restrict__ toks, int step,
    float* __restrict__ logits)        // [NB][NVOC]
{
  __shared__ float osh[32][NB];
  __shared__ float wsh[32][72];
  __shared__ int hist[NB][3];
  int tid = threadIdx.x;
  int vbase = blockIdx.x * 64;
  int vl = (tid & 31) * 2;
  int b0 = (tid >> 5) * 16;
  if (tid < NB){
    hist[tid][0] = (step >= 1) ? toks[(size_t)tid * NSTEPS + step - 1] : -1;
    hist[tid][1] = (step >= 2) ? toks[(size_t)tid * NSTEPS + step - 2] : -1;
    hist[tid][2] = (step >= 3) ? toks[(size_t)tid * NSTEPS + step - 3] : -1;
  }
  float acc0[16], acc1[16];
  #pragma unroll
  for (int i = 0; i < 16; i++){ acc0[i] = 0.f; acc1[i] = 0.f; }

  for (int hc = 0; hc < NH; hc += 32){
    __syncthreads();
    #pragma unroll
    for (int q = tid; q < 1024; q += 256){
      int kk = q >> 5;
      int bb = (q & 31) << 2;
      *(float4*)&osh[kk][bb] = *(const float4*)(o2t + (size_t)(hc + kk) * NB + bb);
    }
    #pragma unroll
    for (int q = tid; q < 512; q += 256){
      int vr = q >> 3;
      int f4 = q & 7;
      float4 w = *(const float4*)(outw + (size_t)(vbase + vr) * NH + hc + f4 * 4);
      wsh[f4*4 + 0][vr] = w.x;
      wsh[f4*4 + 1][vr] = w.y;
      wsh[f4*4 + 2][vr] = w.z;
      wsh[f4*4 + 3][vr] = w.w;
    }
    __syncthreads();
    #pragma unroll 4
    for (int hl = 0; hl < 32; hl++){
      float w0 = wsh[hl][vl];
      float w1 = wsh[hl][vl + 1];
      #pragma unroll
      for (int bq = 0; bq < 4; bq++){
        float4 a = *(const float4*)&osh[hl][b0 + bq * 4];
        acc0[bq*4+0] = fmaf(a.x, w0, acc0[bq*4+0]);
        acc1[bq*4+0] = fmaf(a.x, w1, acc1[bq*4+0]);
        acc0[bq*4+1] = fmaf(a.y, w0, acc0[bq*4+1]);
        acc1[bq*4+1] = fmaf(a.y, w1, acc1[bq*4+1]);
        acc0[bq*4+2] = fmaf(a.z, w0, acc0[bq*4+2]);
        acc1[bq*4+2] = fmaf(a.z, w1, acc1[bq*4+2]);
        acc0[bq*4+3] = fmaf(a.w, w0, acc0[bq*4+3]);
        acc1[bq*4+3] = fmaf(a.w, w1, acc1[bq*4+3]);
      }
    }
  }
  __syncthreads();
  int v0 = vbase + vl;
  int v1 = v0 + 1;
  float ob0 = outb[v0], ob1 = outb[v1];
  #pragma unroll
  for (int i = 0; i < 16; i++){
    int b = b0 + i;
    float l0 = acc0[i] + ob0;
    float l1 = acc1[i] + ob1;
    int h1v = hist[b][0], h2v = hist[b][1], h3v = hist[b][2];
    if (v0 == h1v || v0 == h2v || v0 == h3v) l0 -= 2.0f;
    if (v1 == h1v || v1 == h2v || v1 == h3v) l1 -= 2.0f;
    l0 = l0 / 0.8f;
    l1 = l1 / 0.8f;
    *(float2*)(logits + (size_t)b * NVOC + v0) = make_float2(l0, l1);
  }
}

// ---------------- fused sampler: rowstats + radix sort + cumsum + gumbel pick ---
// This round: phase 2 (p-transform + B writeback) and phase 3 (lane-0 serial
// cumsum) are PIPELINED per 4000-element chunk: all threads transform chunk
// c+1 while lane 0 scans chunk c. Add order of the scan is the identical
// element-ascending chain (chunks are whole 32-groups; same group re-walk)
// -> bit-identical crossing. B chunk visibility: each chunk's writes precede
// the barrier before lane 0 consumes it (same guarantee as the old 2-phase
// structure). Expected: phase2+3 ~75us serial -> ~45-50us pipelined.
__global__ __launch_bounds__(1024)
__attribute__((amdgpu_waves_per_eu(4, 4))) void k_sample(
    const float* __restrict__ logits,
    float* __restrict__ sortbuf,    // sorted values (NB x SORTSTRIDE)
    int* __restrict__ toks,
    int step)
{
  int b = blockIdx.x, tid = threadIdx.x;
  int lane = tid & 63, w = tid >> 6;
  const float* lrow = logits + (size_t)b * NVOC;
  float* B = sortbuf + (size_t)b * SORTSTRIDE;
  __shared__ __align__(16) float row[NVOC];            // 125 KB
  __shared__ __align__(16) unsigned int offs[OFFS_SIZE]; // 16.1 KB; reused as ra/redv/redi
  __shared__ int wtot[16];
  __shared__ float sh_tval;
  __shared__ int sh_ckeep;

  // ---- phase 0a: row max, 1024-wide (order-free) ----
  float* ra = (float*)offs;
  {
    const float4* lr4 = (const float4*)lrow;
    float mx = -INFINITY;
    for (int i = tid; i < NVOC/4; i += 1024){
      float4 v = lr4[i];
      mx = fmaxf(mx, fmaxf(fmaxf(v.x, v.y), fmaxf(v.z, v.w)));
    }
    ra[tid] = mx;
  }
  __syncthreads();
  for (int s = 512; s > 0; s >>= 1){
    if (tid < s) ra[tid] = fmaxf(ra[tid], ra[tid + s]);
    __syncthreads();
  }
  float M = ra[0];
  __syncthreads();
  // ---- phase 0b: Z — EXACT 256-thread strided order (bit-sensitive) ----
  if (tid < 256){
    const float4* lr4 = (const float4*)lrow;
    float z = 0.f;
    for (int i = tid; i < NVOC/4; i += 256){
      float4 v = lr4[i];
      z += expf(v.x - M) + expf(v.y - M) + expf(v.z - M) + expf(v.w - M);
    }
    ra[tid] = z;
  }
  __syncthreads();
  for (int s = 128; s > 0; s >>= 1){
    if (tid < s) ra[tid] += ra[tid + s];
    __syncthreads();
  }
  float Z = ra[0];
  __syncthreads();

  // ---- phase 1: 4-pass LDS-resident radix ----
  int ebase = w * 2048;
  int qmax = (NVOC - ebase) >> 6;               // waves 0-14: 32, wave 15: 20
  if (qmax > 32) qmax = 32;
  unsigned long long below = (1ull << lane) - 1ull;
  int wbase = w * OFFS_STRIDE;

  float vreg[32];
  unsigned int lofs[16];   // two 16-bit local slots per word (pre+rank <= 2047)

  for (int pass = 0; pass < 4; pass++){
    int sh = pass * 8;

    if (pass == 0){
      #pragma unroll
      for (int q = 0; q < 32; q++)
        if (q < qmax) vreg[q] = lrow[ebase + q * 64 + lane];
    } else {
      #pragma unroll
      for (int q = 0; q < 32; q++)
        if (q < qmax) vreg[q] = row[ebase + q * 64 + lane];
    }
    for (int i = tid; i < OFFS_SIZE; i += 1024) offs[i] = 0u;
    __syncthreads();

    // (b) histogram + local-slot record: ballot-match per q (ONCE);
    // all digit-group lanes broadcast-read pre, leader writes pre+cnt.
    #pragma unroll
    for (int q = 0; q < 32; q++){
      if (q < qmax){
        unsigned u = __float_as_uint(vreg[q]);
        unsigned key = ~(u ^ ((unsigned)(((int)u) >> 31) | 0x80000000u));
        unsigned d = (key >> sh) & 255u;
        unsigned long long m = ~0ull;
        #pragma unroll
        for (int bit = 0; bit < 8; bit++){
          unsigned long long bb = __ballot((d >> bit) & 1u);
          m &= ((d >> bit) & 1u) ? bb : ~bb;
        }
        int rank = __popcll(m & below);
        int cnt  = __popcll(m);
        unsigned pre = offs[wbase + d];
        unsigned lo = pre + (unsigned)rank;
        if ((q & 1) == 0) lofs[q >> 1] = lo;
        else              lofs[q >> 1] |= lo << 16;
        if (rank == 0) offs[wbase + d] = pre + (unsigned)cnt;
      }
    }
    __syncthreads();

    // (c) exclusive prefix over flat (d-major) order; same ownership as before
    int d_own = tid >> 2;
    int w0 = (tid & 3) * 4;
    unsigned l0 = offs[(w0+0) * OFFS_STRIDE + d_own];
    unsigned l1 = offs[(w0+1) * OFFS_STRIDE + d_own];
    unsigned l2 = offs[(w0+2) * OFFS_STRIDE + d_own];
    unsigned l3 = offs[(w0+3) * OFFS_STRIDE + d_own];
    int v = (int)(l0 + l1 + l2 + l3);
    int inc = v;
    #pragma unroll
    for (int dd = 1; dd < 64; dd <<= 1){
      int o = __shfl_up(inc, dd);
      if (lane >= dd) inc += o;
    }
    if (lane == 63) wtot[w] = inc;
    __syncthreads();
    int woff = 0;
    #pragma unroll
    for (int ww = 0; ww < 16; ww++) woff += (ww < w) ? wtot[ww] : 0;
    unsigned run = (unsigned)(woff + inc - v);
    offs[(w0+0) * OFFS_STRIDE + d_own] = run; run += l0;
    offs[(w0+1) * OFFS_STRIDE + d_own] = run; run += l1;
    offs[(w0+2) * OFFS_STRIDE + d_own] = run; run += l2;
    offs[(w0+3) * OFFS_STRIDE + d_own] = run;
    __syncthreads();

    // (d) scatter: pure parallel writes — no ballots, no bump, no ordering.
    // addr = excl_base[w][d] + (pre + rank) == old leader-bump placement.
    #pragma unroll
    for (int q = 0; q < 32; q++){
      if (q < qmax){
        unsigned u = __float_as_uint(vreg[q]);
        unsigned key = ~(u ^ ((unsigned)(((int)u) >> 31) | 0x80000000u));
        unsigned d = (key >> sh) & 255u;
        unsigned lo = (lofs[q >> 1] >> ((q & 1) * 16)) & 0xFFFFu;
        row[offs[wbase + d] + lo] = vreg[q];
      }
    }
    __syncthreads();
  }

  // ---- phase 2+3 pipelined: chunked {B writeback + p-transform} || serial scan
  // 8 chunks x 4000 floats (1000 float4, threads 0..999). Lane 0 scans chunk c
  // while the block transforms chunk c+1. Scan add order == old monolithic
  // chain; per-32-group crossing check + re-walk -> bit-identical ks.
  {
    float4* b4 = (float4*)B;
    float4* r4 = (float4*)row;
    // prologue: chunk 0
    if (tid < 1000){
      float4 v = r4[tid];
      b4[tid] = v;
      float4 p;
      p.x = expf(v.x - M) / Z;
      p.y = expf(v.y - M) / Z;
      p.z = expf(v.z - M) / Z;
      p.w = expf(v.w - M) / Z;
      r4[tid] = p;
    }
    __syncthreads();

    float s = 0.f;
    int done = 0;
    for (int c = 0; c < 8; c++){
      // produce chunk c+1 (waves 0-15; lane 0 also helps, tiny share)
      if (c < 7 && tid < 1000){
        int i = (c + 1) * 1000 + tid;
        float4 v = r4[i];
        b4[i] = v;
        float4 p;
        p.x = expf(v.x - M) / Z;
        p.y = expf(v.y - M) / Z;
        p.z = expf(v.z - M) / Z;
        p.w = expf(v.w - M) / Z;
        r4[i] = p;
      }
      // consume chunk c (lane 0 serial; 125 groups of 32)
      if (tid == 0 && !done){
        const float* base = &row[c * 4000];
        for (int g = 0; g < 125; g++){
          float prev = s;
          const float* pp = base + g * 32;
          #pragma unroll
          for (int q = 0; q < 32; q++) s += pp[q];
          if (s > 0.9f){
            float t = prev;
            int kk = 31;
            for (int q = 0; q < 32; q++){
              t = t + pp[q];                 // same values, same order
              if (t > 0.9f){ kk = q; break; }
            }
            int ks = c * 4000 + g * 32 + kk;
            float tv = B[ks];
            int jlo = ks;
            while (jlo > 0 && B[jlo - 1] == tv) jlo--;
            sh_tval = tv;
            sh_ckeep = ks + 1 - jlo;         // tokens equal to tv kept
            done = 1;
            break;
          }
        }
      }
      __syncthreads();   // chunk c+1 ready (LDS+global) & scan c finished
    }
    if (tid == 0 && !done){
      int ks = NVOC - 1;
      float tv = B[ks];
      int jlo = ks;
      while (jlo > 0 && B[jlo - 1] == tv) jlo--;
      sh_tval = tv;
      sh_ckeep = ks + 1 - jlo;
    }
  }
  __syncthreads();

  // ---- phase 4: gumbel-max over kept set ----
  float tval = sh_tval;
  int ckeep = sh_ckeep;
  float* redv = (float*)offs;              // 4 KB
  int*   redi = (int*)(offs + 1024);       // next 4 KB

  int stt = tid * 32;
  int en = min(stt + 32, NVOC);
  int eqc = 0;
  for (int i = stt; i < en; i++) eqc += (lrow[i] == tval) ? 1 : 0;
  int inc = eqc;
  #pragma unroll
  for (int dd = 1; dd < 64; dd <<= 1){
    int o = __shfl_up(inc, dd);
    if (lane >= dd) inc += o;
  }
  if (lane == 63) wtot[w] = inc;
  __syncthreads();
  int woff = 0;
  #pragma unroll
  for (int ww = 0; ww < 16; ww++) woff += (ww < w) ? wtot[ww] : 0;
  int eqrank = woff + inc - eqc;

  uint32_t fk0, fk1;
  threefry2x32(0u, 42u, 0u, (uint32_t)step, fk0, fk1);   // fold_in(key(42), step)
  float best = -INFINITY;
  int besti = NVOC;
  for (int i = stt; i < en; i++){
    float l = lrow[i];
    bool keep;
    if (l > tval) keep = true;
    else if (l == tval){ keep = (eqrank < ckeep); eqrank++; }
    else keep = false;
    if (keep){
      uint32_t o0, o1;
      threefry2x32(fk0, fk1, 0u, (uint32_t)(b * NVOC + i), o0, o1);
      uint32_t bits = o0 ^ o1;
      uint32_t fb2 = (bits >> 9) | 0x3f800000u;
      float u = __uint_as_float(fb2) - 1.0f;
      if (u == 0.0f) u = 1.17549435e-38f;   // minval = tiny
      float gum = -logf(-logf(u));
      float cand = l + gum;
      if (cand > best){ best = cand; besti = i; }
    }
  }
  redv[tid] = best;
  redi[tid] = besti;
  __syncthreads();
  for (int s = 512; s > 0; s >>= 1){
    if (tid < s){
      float ov = redv[tid + s]; int oi = redi[tid + s];
      if (ov > redv[tid] || (ov == redv[tid] && oi < redi[tid])){
        redv[tid] = ov; redi[tid] = oi;
      }
    }
    __syncthreads();
  }
  if (tid == 0) toks[(size_t)b * NSTEPS + step] = redi[0];
}

// ---------------- host launcher -------------------------------------------------
extern "C" void kernel_launch(void* const* d_in, const int* in_sizes, int n_in,
                              void* d_out, int out_size, void* d_ws, size_t ws_size,
                              hipStream_t stream)
{
  (void)in_sizes; (void)n_in; (void)out_size;
  const float* thought = (const float*)d_in[0];
  const float* vfeat   = (const float*)d_in[1];
  const float* emb     = (const float*)d_in[2];
  const float* w_ih0   = (const float*)d_in[3];
  const float* w_hh0   = (const float*)d_in[4];
  const float* b_ih0   = (const float*)d_in[5];
  const float* b_hh0   = (const float*)d_in[6];
  const float* w_ih1   = (const float*)d_in[7];
  const float* w_hh1   = (const float*)d_in[8];
  const float* b_ih1   = (const float*)d_in[9];
  const float* b_hh1   = (const float*)d_in[10];
  const float* gw1     = (const float*)d_in[11];
  const float* gb1     = (const float*)d_in[12];
  const float* gw2     = (const float*)d_in[13];
  const float* gb2     = (const float*)d_in[14];
  const float* out_w   = (const float*)d_in[15];
  const float* out_b   = (const float*)d_in[16];
  const float* vis_w   = (const float*)d_in[17];
  const float* vis_b   = (const float*)d_in[18];
  const float* ln_g    = (const float*)d_in[19];
  const float* ln_b    = (const float*)d_in[20];
  int* toks = (int*)d_out;

  char* ws = (char*)d_ws;
  size_t off = 0;
  auto alloc = [&](size_t bytes) -> void* {
    void* p = ws + off;
    off += (bytes + 255) & ~(size_t)255;
    return p;
  };
  float* vp      = (float*)alloc((size_t)NB * NNV * NH * 4);
  float* h0a     = (float*)alloc((size_t)NH * NB * 4);
  float* h0b     = (float*)alloc((size_t)NH * NB * 4);
  float* c0a     = (float*)alloc((size_t)NH * NB * 4);
  float* c0b     = (float*)alloc((size_t)NH * NB * 4);
  float* h1a     = (float*)alloc((size_t)NH * NB * 4);
  float* h1b     = (float*)alloc((size_t)NH * NB * 4);
  float* c1a     = (float*)alloc((size_t)NH * NB * 4);
  float* c1b     = (float*)alloc((size_t)NH * NB * 4);
  float* o2t     = (float*)alloc((size_t)NH * NB * 4);
  float* logits  = (float*)alloc((size_t)NB * NVOC * 4);
  float* sortbuf = (float*)alloc((size_t)NB * SORTSTRIDE * 4);// sorted rows
  if (off > ws_size) return;  // insufficient scratch: fail loudly via wrong output

  k_visgemm<<<dim3(VTOK / 64, NH / 64), 256, 0, stream>>>(vfeat, vis_w, vis_b, vp);
  k_visln<<<VTOK, 256, 0, stream>>>(ln_g, ln_b, vp);
  k_init<<<(NH * NB + 255) / 256, 256, 0, stream>>>(thought, h0a, c0a, h1a, c1a);

  for (int step = 0; step < NSTEPS; step++){
    float *h0r, *h0w, *c0r, *c0w, *h1r, *h1w, *c1r, *c1w;
    if ((step & 1) == 0){
      h0r = h0a; h0w = h0b; c0r = c0a; c0w = c0b;
      h1r = h1a; h1w = h1b; c1r = c1a; c1w = c1b;
    } else {
      h0r = h0b; h0w = h0a; c0r = c0b; c0w = c0a;
      h1r = h1b; h1w = h1a; c1r = c1b; c1w = c1a;
    }
    k_lstm<NE><<<dim3(32, 2), 256, 0, stream>>>(
        w_ih0, w_hh0, b_ih0, b_hh0, emb, toks, step, h0r, c0r, h0w, c0w);
    k_lstm<NH><<<dim3(32, 2), 256, 0, stream>>>(
        w_ih1, w_hh1, b_ih1, b_hh1, h0w, toks, step, h1r, c1r, h1w, c1w);
    k_gateattn<<<NB, 256, 0, stream>>>(h1w, gw1, gb1, gw2, gb2, vp, o2t);
    k_logits<<<NVOC / 64, 256, 0, stream>>>(o2t, out_w, out_b, toks, step, logits);
    k_sample<<<NB, 1024, 0, stream>>>(logits, sortbuf, toks, step);
  }
}

// Round 14
// 17671.884 us; speedup vs baseline: 1.1089x; 1.1089x over previous
//
#include <hip/hip_runtime.h>
#include <stdint.h>

#define NB 128      // batch
#define NH 512      // hidden
#define NE 128      // embedding dim
#define NVOC 32000  // vocab
#define NNV 196     // visual tokens
#define NDV 256     // visual dim
#define NSTEPS 32
#define SORTSTRIDE 32768
#define VTOK (NB * NNV)   // 25088 visual token rows

// offs layout: [w][d] with padded stride 257 (257 % 32 == 1 -> bank = (w+d)%32).
#define OFFS_STRIDE 257
#define OFFS_SIZE (16 * OFFS_STRIDE)   // 4112 words

// ---------------- Threefry-2x32 (20 rounds), exact JAX semantics --------------
static __device__ __forceinline__ uint32_t rotl32(uint32_t x, int r){
  return (x << r) | (x >> (32 - r));
}

static __device__ __forceinline__ void threefry2x32(uint32_t k0, uint32_t k1,
    uint32_t x0, uint32_t x1, uint32_t &o0, uint32_t &o1){
  uint32_t k2 = k0 ^ k1 ^ 0x1BD11BDAu;
  x0 += k0; x1 += k1;
#define TF_RND(r) { x0 += x1; x1 = rotl32(x1,(r)); x1 ^= x0; }
  TF_RND(13) TF_RND(15) TF_RND(26) TF_RND(6)
  x0 += k1; x1 += k2 + 1u;
  TF_RND(17) TF_RND(29) TF_RND(16) TF_RND(24)
  x0 += k2; x1 += k0 + 2u;
  TF_RND(13) TF_RND(15) TF_RND(26) TF_RND(6)
  x0 += k0; x1 += k1 + 3u;
  TF_RND(17) TF_RND(29) TF_RND(16) TF_RND(24)
  x0 += k1; x1 += k2 + 4u;
  TF_RND(13) TF_RND(15) TF_RND(26) TF_RND(6)
  x0 += k2; x1 += k0 + 5u;
#undef TF_RND
  o0 = x0; o1 = x1;
}

// ---------------- visual projection GEMM (tiled, coalesced) -------------------
__global__ __launch_bounds__(256) void k_visgemm(
    const float* __restrict__ vf,     // [VTOK][NDV]
    const float* __restrict__ vis_w,  // [NH][NDV]
    const float* __restrict__ vis_b,
    float* __restrict__ vp)           // [VTOK][NH] (raw, pre-LN)
{
  __shared__ float As[64][68];
  __shared__ float Ws[64][68];
  int tid = threadIdx.x;
  int tx = tid & 15;          // h sub-tile
  int ty = tid >> 4;          // token sub-tile
  int mb = blockIdx.x * 64;   // token base
  int hb = blockIdx.y * 64;   // hidden base
  int m_l = ty * 4, h_l = tx * 4;

  float acc[4][4];
  #pragma unroll
  for (int i = 0; i < 4; i++)
    #pragma unroll
    for (int j = 0; j < 4; j++) acc[i][j] = 0.f;

  for (int kc = 0; kc < NDV; kc += 64){
    __syncthreads();
    for (int q = tid; q < 1024; q += 256){
      int m = q >> 4, k4 = (q & 15) << 2;
      *(float4*)&As[m][k4] = *(const float4*)(vf + (size_t)(mb + m) * NDV + kc + k4);
    }
    for (int q = tid; q < 1024; q += 256){
      int h = q >> 4, k4 = (q & 15) << 2;
      *(float4*)&Ws[h][k4] = *(const float4*)(vis_w + (size_t)(hb + h) * NDV + kc + k4);
    }
    __syncthreads();
#define FMA4(i,j,av,wv) \
    acc[i][j] = fmaf(av.x, wv.x, acc[i][j]); \
    acc[i][j] = fmaf(av.y, wv.y, acc[i][j]); \
    acc[i][j] = fmaf(av.z, wv.z, acc[i][j]); \
    acc[i][j] = fmaf(av.w, wv.w, acc[i][j]);
    #pragma unroll 4
    for (int kk = 0; kk < 64; kk += 4){
      float4 a0 = *(const float4*)&As[m_l + 0][kk];
      float4 a1 = *(const float4*)&As[m_l + 1][kk];
      float4 a2 = *(const float4*)&As[m_l + 2][kk];
      float4 a3 = *(const float4*)&As[m_l + 3][kk];
      float4 w0 = *(const float4*)&Ws[h_l + 0][kk];
      float4 w1 = *(const float4*)&Ws[h_l + 1][kk];
      float4 w2 = *(const float4*)&Ws[h_l + 2][kk];
      float4 w3 = *(const float4*)&Ws[h_l + 3][kk];
      FMA4(0,0,a0,w0) FMA4(0,1,a0,w1) FMA4(0,2,a0,w2) FMA4(0,3,a0,w3)
      FMA4(1,0,a1,w0) FMA4(1,1,a1,w1) FMA4(1,2,a1,w2) FMA4(1,3,a1,w3)
      FMA4(2,0,a2,w0) FMA4(2,1,a2,w1) FMA4(2,2,a2,w2) FMA4(2,3,a2,w3)
      FMA4(3,0,a3,w0) FMA4(3,1,a3,w1) FMA4(3,2,a3,w2) FMA4(3,3,a3,w3)
    }
#undef FMA4
  }

  float4 bias = *(const float4*)(vis_b + hb + h_l);
  #pragma unroll
  for (int i = 0; i < 4; i++){
    float4 o;
    o.x = acc[i][0] + bias.x;
    o.y = acc[i][1] + bias.y;
    o.z = acc[i][2] + bias.z;
    o.w = acc[i][3] + bias.w;
    *(float4*)(vp + (size_t)(mb + m_l + i) * NH + hb + h_l) = o;
  }
}

// ---------------- LayerNorm over vp rows, in place ----------------------------
__global__ __launch_bounds__(256) void k_visln(
    const float* __restrict__ ln_g, const float* __restrict__ ln_b,
    float* __restrict__ vp)
{
  int bn = blockIdx.x;
  int tid = threadIdx.x;
  __shared__ float red[256];
  float* op = vp + (size_t)bn * NH;
  float out0 = op[tid];
  float out1 = op[tid + 256];
  red[tid] = out0 + out1; __syncthreads();
  for (int s = 128; s > 0; s >>= 1){ if (tid < s) red[tid] += red[tid + s]; __syncthreads(); }
  float mu = red[0] * (1.0f / (float)NH);
  __syncthreads();
  float d0 = out0 - mu, d1 = out1 - mu;
  red[tid] = d0*d0 + d1*d1; __syncthreads();
  for (int s = 128; s > 0; s >>= 1){ if (tid < s) red[tid] += red[tid + s]; __syncthreads(); }
  float var = red[0] * (1.0f / (float)NH);
  float r = 1.0f / sqrtf(var + 1e-5f);
  op[tid]       = d0 * r * ln_g[tid]       + ln_b[tid];
  op[tid + 256] = d1 * r * ln_g[tid + 256] + ln_b[tid + 256];
}

// ---------------- init hidden states ------------------------------------------
__global__ void k_init(const float* __restrict__ thought,
                       float* __restrict__ h0, float* __restrict__ c0,
                       float* __restrict__ h1, float* __restrict__ c1)
{
  int id = blockIdx.x * 256 + threadIdx.x;
  if (id >= NH * NB) return;
  int k = id >> 7;
  int b = id & 127;
  float v = thought[(size_t)b * NH + k];
  h0[id] = v; h1[id] = v; c0[id] = 0.f; c1[id] = 0.f;
}

// ---------------- fused LSTM layer (GEMM + cell) -------------------------------
// Batch tile 64 -> 32 (dim3(32,4) = 128 blocks, was 64). 64 blocks left 75% of
// the 256 CUs idle. Per-output accumulation chains are unchanged (same kc
// ascent, same fmaf order per (j,b) output) -> bit-identical; a thread now
// owns 2 batch elems (acc[4][2], float2 loads/stores) instead of 4.
template<int K1>
__global__ __launch_bounds__(256) void k_lstm(
    const float* __restrict__ wih, const float* __restrict__ whh,
    const float* __restrict__ bih, const float* __restrict__ bhh,
    const float* __restrict__ a1,
    const int*   __restrict__ toks, int step,
    const float* __restrict__ hprev, const float* __restrict__ cprev,
    float* __restrict__ hout, float* __restrict__ cout)
{
  __shared__ float As[64][36];        // 32-wide batch tile, +4 pad
  __shared__ float Ws[4 * 16 * 68];
  __shared__ int tokl[32];
  int tid = threadIdx.x;
  int jl = tid & 15;
  int bg = tid >> 4;
  int jbase = blockIdx.x * 16;
  int j = jbase + jl;
  int bblk = blockIdx.y * 32;
  int bl = bg * 2;
  if (K1 == NE){
    if (tid < 32) tokl[tid] = (step == 0) ? 1 : toks[(size_t)(bblk + tid) * NSTEPS + step - 1];
  }
  __syncthreads();

  float acc[4][2];
  #pragma unroll
  for (int g = 0; g < 4; g++)
    #pragma unroll
    for (int e = 0; e < 2; e++) acc[g][e] = 0.f;

  for (int part = 0; part < 2; part++){
    const float* Wsrc = part ? whh : wih;
    const float* Asrc = part ? hprev : a1;
    const int K = part ? NH : K1;
    const bool gather = (!part) && (K1 == NE);
    for (int kc = 0; kc < K; kc += 64){
      __syncthreads();
      for (int q = tid; q < 512; q += 256){
        int kk = q >> 3;
        int bb = (q & 7) << 2;
        float4 v;
        if (gather){
          v.x = Asrc[(size_t)tokl[bb+0] * NE + kc + kk];
          v.y = Asrc[(size_t)tokl[bb+1] * NE + kc + kk];
          v.z = Asrc[(size_t)tokl[bb+2] * NE + kc + kk];
          v.w = Asrc[(size_t)tokl[bb+3] * NE + kc + kk];
        } else {
          v = *(const float4*)(Asrc + (size_t)(kc + kk) * NB + bblk + bb);
        }
        *(float4*)&As[kk][bb] = v;
      }
      for (int q = tid; q < 1024; q += 256){
        int r = q >> 4;
        int f = q & 15;
        int g = r >> 4;
        int jj = r & 15;
        float4 w = *(const float4*)(Wsrc + (size_t)(g * NH + jbase + jj) * K + kc + f * 4);
        float* wd = &Ws[(g * 16 + jj) * 68 + f * 4];
        wd[0] = w.x; wd[1] = w.y; wd[2] = w.z; wd[3] = w.w;
      }
      __syncthreads();
      #pragma unroll 2
      for (int kk = 0; kk < 64; kk += 4){
        float2 a0  = *(const float2*)&As[kk + 0][bl];
        float2 a1v = *(const float2*)&As[kk + 1][bl];
        float2 a2  = *(const float2*)&As[kk + 2][bl];
        float2 a3  = *(const float2*)&As[kk + 3][bl];
        #pragma unroll
        for (int g = 0; g < 4; g++){
          float4 w = *(const float4*)&Ws[(g * 16 + jl) * 68 + kk];
          acc[g][0] = fmaf(a0.x, w.x, acc[g][0]);
          acc[g][1] = fmaf(a0.y, w.x, acc[g][1]);
          acc[g][0] = fmaf(a1v.x, w.y, acc[g][0]);
          acc[g][1] = fmaf(a1v.y, w.y, acc[g][1]);
          acc[g][0] = fmaf(a2.x, w.z, acc[g][0]);
          acc[g][1] = fmaf(a2.y, w.z, acc[g][1]);
          acc[g][0] = fmaf(a3.x, w.w, acc[g][0]);
          acc[g][1] = fmaf(a3.y, w.w, acc[g][1]);
        }
      }
    }
  }

  float bi[4];
  #pragma unroll
  for (int g = 0; g < 4; g++) bi[g] = bih[g * NH + j] + bhh[g * NH + j];
  int b0g = bblk + bl;
  float2 cp = *(const float2*)(cprev + (size_t)j * NB + b0g);
  float cpv[2] = {cp.x, cp.y};
  float hs[2], cs[2];
  #pragma unroll
  for (int e = 0; e < 2; e++){
    float zi = acc[0][e] + bi[0];
    float zf = acc[1][e] + bi[1];
    float zg = acc[2][e] + bi[2];
    float zo = acc[3][e] + bi[3];
    float si = 1.f / (1.f + expf(-zi));
    float sf = 1.f / (1.f + expf(-zf));
    float so = 1.f / (1.f + expf(-zo));
    float tg = tanhf(zg);
    float c2 = sf * cpv[e] + si * tg;
    cs[e] = c2;
    hs[e] = so * tanhf(c2);
  }
  *(float2*)(cout + (size_t)j * NB + b0g) = make_float2(cs[0], cs[1]);
  *(float2*)(hout + (size_t)j * NB + b0g) = make_float2(hs[0], hs[1]);
}

// ---------------- gate + visual attention --------------------------------------
__global__ __launch_bounds__(256) void k_gateattn(
    const float* __restrict__ h1t,
    const float* __restrict__ gw1, const float* __restrict__ gb1,
    const float* __restrict__ gw2, const float* __restrict__ gb2,
    const float* __restrict__ vp,
    float* __restrict__ o2t)
{
  int b = blockIdx.x;
  int tid = threadIdx.x;
  __shared__ float hsm[NH];
  __shared__ float tsm[NH];
  __shared__ float osm[NH];
  __shared__ float aw[NNV];
  __shared__ float red[256];
  for (int h = tid; h < NH; h += 256) hsm[h] = h1t[(size_t)h * NB + b];
  __syncthreads();
  for (int jj = tid; jj < NH; jj += 256){
    const float4* wr = (const float4*)(gw1 + (size_t)jj * NH);
    const float4* h4 = (const float4*)hsm;
    float acc = 0.f;
    #pragma unroll 4
    for (int k = 0; k < NH/4; k++){
      float4 w = wr[k]; float4 hh = h4[k];
      acc = fmaf(hh.x, w.x, acc);
      acc = fmaf(hh.y, w.y, acc);
      acc = fmaf(hh.z, w.z, acc);
      acc = fmaf(hh.w, w.w, acc);
    }
    tsm[jj] = tanhf(acc + gb1[jj]);
  }
  __syncthreads();
  float part = 0.f;
  for (int jj = tid; jj < NH; jj += 256) part = fmaf(tsm[jj], gw2[jj], part);
  red[tid] = part; __syncthreads();
  for (int s = 128; s > 0; s >>= 1){ if (tid < s) red[tid] += red[tid + s]; __syncthreads(); }
  float gate = 1.f / (1.f + expf(-(red[0] + gb2[0])));
  __syncthreads();
  for (int h = tid; h < NH; h += 256) osm[h] = hsm[h] * gate;
  __syncthreads();
  const float* vpb = vp + (size_t)b * NNV * NH;
  float sc = 0.f;
  if (tid < NNV){
    const float4* vr = (const float4*)(vpb + (size_t)tid * NH);
    const float4* o4 = (const float4*)osm;
    float accv = 0.f;
    #pragma unroll 4
    for (int k = 0; k < NH/4; k++){
      float4 v = vr[k]; float4 oo = o4[k];
      accv = fmaf(oo.x, v.x, accv);
      accv = fmaf(oo.y, v.y, accv);
      accv = fmaf(oo.z, v.z, accv);
      accv = fmaf(oo.w, v.w, accv);
    }
    sc = accv / 22.62741699796952f;   // scores / sqrt(512)
  }
  red[tid] = (tid < NNV) ? sc : -INFINITY;
  __syncthreads();
  for (int s = 128; s > 0; s >>= 1){ if (tid < s) red[tid] = fmaxf(red[tid], red[tid + s]); __syncthreads(); }
  float mx = red[0];
  __syncthreads();
  float ev = (tid < NNV) ? expf(sc - mx) : 0.f;
  red[tid] = ev; __syncthreads();
  for (int s = 128; s > 0; s >>= 1){ if (tid < s) red[tid] += red[tid + s]; __syncthreads(); }
  float zs = red[0];
  if (tid < NNV) aw[tid] = ev / zs;
  __syncthreads();
  for (int h = tid; h < NH; h += 256){
    float accv = 0.f;
    for (int n = 0; n < NNV; n++) accv = fmaf(aw[n], vpb[(size_t)n * NH + h], accv);
    o2t[(size_t)h * NB + b] = osm[h] + accv;
  }
}

// ---------------- logits GEMM + rep-penalty + temperature -----------------------
__global__ __launch_bounds__(256, 4) void k_logits(
    const float* __restrict__ o2t,     // [NH][NB]
    const float* __restrict__ outw,    // [NVOC][NH]
    const float* __restrict__ outb,
    const int* __restrict__ toks, int step,
    float* __restrict__ logits)        // [NB][NVOC]
{
  __shared__ float osh[32][NB];
  __shared__ float wsh[32][72];
  __shared__ int hist[NB][3];
  int tid = threadIdx.x;
  int vbase = blockIdx.x * 64;
  int vl = (tid & 31) * 2;
  int b0 = (tid >> 5) * 16;
  if (tid < NB){
    hist[tid][0] = (step >= 1) ? toks[(size_t)tid * NSTEPS + step - 1] : -1;
    hist[tid][1] = (step >= 2) ? toks[(size_t)tid * NSTEPS + step - 2] : -1;
    hist[tid][2] = (step >= 3) ? toks[(size_t)tid * NSTEPS + step - 3] : -1;
  }
  float acc0[16], acc1[16];
  #pragma unroll
  for (int i = 0; i < 16; i++){ acc0[i] = 0.f; acc1[i] = 0.f; }

  for (int hc = 0; hc < NH; hc += 32){
    __syncthreads();
    #pragma unroll
    for (int q = tid; q < 1024; q += 256){
      int kk = q >> 5;
      int bb = (q & 31) << 2;
      *(float4*)&osh[kk][bb] = *(const float4*)(o2t + (size_t)(hc + kk) * NB + bb);
    }
    #pragma unroll
    for (int q = tid; q < 512; q += 256){
      int vr = q >> 3;
      int f4 = q & 7;
      float4 w = *(const float4*)(outw + (size_t)(vbase + vr) * NH + hc + f4 * 4);
      wsh[f4*4 + 0][vr] = w.x;
      wsh[f4*4 + 1][vr] = w.y;
      wsh[f4*4 + 2][vr] = w.z;
      wsh[f4*4 + 3][vr] = w.w;
    }
    __syncthreads();
    #pragma unroll 4
    for (int hl = 0; hl < 32; hl++){
      float w0 = wsh[hl][vl];
      float w1 = wsh[hl][vl + 1];
      #pragma unroll
      for (int bq = 0; bq < 4; bq++){
        float4 a = *(const float4*)&osh[hl][b0 + bq * 4];
        acc0[bq*4+0] = fmaf(a.x, w0, acc0[bq*4+0]);
        acc1[bq*4+0] = fmaf(a.x, w1, acc1[bq*4+0]);
        acc0[bq*4+1] = fmaf(a.y, w0, acc0[bq*4+1]);
        acc1[bq*4+1] = fmaf(a.y, w1, acc1[bq*4+1]);
        acc0[bq*4+2] = fmaf(a.z, w0, acc0[bq*4+2]);
        acc1[bq*4+2] = fmaf(a.z, w1, acc1[bq*4+2]);
        acc0[bq*4+3] = fmaf(a.w, w0, acc0[bq*4+3]);
        acc1[bq*4+3] = fmaf(a.w, w1, acc1[bq*4+3]);
      }
    }
  }
  __syncthreads();
  int v0 = vbase + vl;
  int v1 = v0 + 1;
  float ob0 = outb[v0], ob1 = outb[v1];
  #pragma unroll
  for (int i = 0; i < 16; i++){
    int b = b0 + i;
    float l0 = acc0[i] + ob0;
    float l1 = acc1[i] + ob1;
    int h1v = hist[b][0], h2v = hist[b][1], h3v = hist[b][2];
    if (v0 == h1v || v0 == h2v || v0 == h3v) l0 -= 2.0f;
    if (v1 == h1v || v1 == h2v || v1 == h3v) l1 -= 2.0f;
    l0 = l0 / 0.8f;
    l1 = l1 / 0.8f;
    *(float2*)(logits + (size_t)b * NVOC + v0) = make_float2(l0, l1);
  }
}

// ---------------- fused sampler: rowstats + radix sort + cumsum + gumbel pick ---
// Round-9 structure (monolithic phases; chunked pipelining of phase 2/3
// measured SLOWER: 335 -> 362 us from per-chunk barrier lockstep).
__global__ __launch_bounds__(1024)
__attribute__((amdgpu_waves_per_eu(4, 4))) void k_sample(
    const float* __restrict__ logits,
    float* __restrict__ sortbuf,    // sorted values (NB x SORTSTRIDE)
    int* __restrict__ toks,
    int step)
{
  int b = blockIdx.x, tid = threadIdx.x;
  int lane = tid & 63, w = tid >> 6;
  const float* lrow = logits + (size_t)b * NVOC;
  float* B = sortbuf + (size_t)b * SORTSTRIDE;
  __shared__ __align__(16) float row[NVOC];            // 125 KB
  __shared__ __align__(16) unsigned int offs[OFFS_SIZE]; // 16.1 KB; reused as ra/redv/redi
  __shared__ int wtot[16];
  __shared__ float sh_tval;
  __shared__ int sh_ckeep;

  // ---- phase 0a: row max, 1024-wide (order-free) ----
  float* ra = (float*)offs;
  {
    const float4* lr4 = (const float4*)lrow;
    float mx = -INFINITY;
    for (int i = tid; i < NVOC/4; i += 1024){
      float4 v = lr4[i];
      mx = fmaxf(mx, fmaxf(fmaxf(v.x, v.y), fmaxf(v.z, v.w)));
    }
    ra[tid] = mx;
  }
  __syncthreads();
  for (int s = 512; s > 0; s >>= 1){
    if (tid < s) ra[tid] = fmaxf(ra[tid], ra[tid + s]);
    __syncthreads();
  }
  float M = ra[0];
  __syncthreads();
  // ---- phase 0b: Z — EXACT 256-thread strided order (bit-sensitive) ----
  if (tid < 256){
    const float4* lr4 = (const float4*)lrow;
    float z = 0.f;
    for (int i = tid; i < NVOC/4; i += 256){
      float4 v = lr4[i];
      z += expf(v.x - M) + expf(v.y - M) + expf(v.z - M) + expf(v.w - M);
    }
    ra[tid] = z;
  }
  __syncthreads();
  for (int s = 128; s > 0; s >>= 1){
    if (tid < s) ra[tid] += ra[tid + s];
    __syncthreads();
  }
  float Z = ra[0];
  __syncthreads();

  // ---- phase 1: 4-pass LDS-resident radix ----
  int ebase = w * 2048;
  int qmax = (NVOC - ebase) >> 6;               // waves 0-14: 32, wave 15: 20
  if (qmax > 32) qmax = 32;
  unsigned long long below = (1ull << lane) - 1ull;
  int wbase = w * OFFS_STRIDE;

  float vreg[32];
  unsigned int lofs[16];   // two 16-bit local slots per word (pre+rank <= 2047)

  for (int pass = 0; pass < 4; pass++){
    int sh = pass * 8;

    if (pass == 0){
      #pragma unroll
      for (int q = 0; q < 32; q++)
        if (q < qmax) vreg[q] = lrow[ebase + q * 64 + lane];
    } else {
      #pragma unroll
      for (int q = 0; q < 32; q++)
        if (q < qmax) vreg[q] = row[ebase + q * 64 + lane];
    }
    for (int i = tid; i < OFFS_SIZE; i += 1024) offs[i] = 0u;
    __syncthreads();

    // (b) histogram + local-slot record: ballot-match per q (ONCE);
    // all digit-group lanes broadcast-read pre, leader writes pre+cnt.
    #pragma unroll
    for (int q = 0; q < 32; q++){
      if (q < qmax){
        unsigned u = __float_as_uint(vreg[q]);
        unsigned key = ~(u ^ ((unsigned)(((int)u) >> 31) | 0x80000000u));
        unsigned d = (key >> sh) & 255u;
        unsigned long long m = ~0ull;
        #pragma unroll
        for (int bit = 0; bit < 8; bit++){
          unsigned long long bb = __ballot((d >> bit) & 1u);
          m &= ((d >> bit) & 1u) ? bb : ~bb;
        }
        int rank = __popcll(m & below);
        int cnt  = __popcll(m);
        unsigned pre = offs[wbase + d];
        unsigned lo = pre + (unsigned)rank;
        if ((q & 1) == 0) lofs[q >> 1] = lo;
        else              lofs[q >> 1] |= lo << 16;
        if (rank == 0) offs[wbase + d] = pre + (unsigned)cnt;
      }
    }
    __syncthreads();

    // (c) exclusive prefix over flat (d-major) order; same ownership as before
    int d_own = tid >> 2;
    int w0 = (tid & 3) * 4;
    unsigned l0 = offs[(w0+0) * OFFS_STRIDE + d_own];
    unsigned l1 = offs[(w0+1) * OFFS_STRIDE + d_own];
    unsigned l2 = offs[(w0+2) * OFFS_STRIDE + d_own];
    unsigned l3 = offs[(w0+3) * OFFS_STRIDE + d_own];
    int v = (int)(l0 + l1 + l2 + l3);
    int inc = v;
    #pragma unroll
    for (int dd = 1; dd < 64; dd <<= 1){
      int o = __shfl_up(inc, dd);
      if (lane >= dd) inc += o;
    }
    if (lane == 63) wtot[w] = inc;
    __syncthreads();
    int woff = 0;
    #pragma unroll
    for (int ww = 0; ww < 16; ww++) woff += (ww < w) ? wtot[ww] : 0;
    unsigned run = (unsigned)(woff + inc - v);
    offs[(w0+0) * OFFS_STRIDE + d_own] = run; run += l0;
    offs[(w0+1) * OFFS_STRIDE + d_own] = run; run += l1;
    offs[(w0+2) * OFFS_STRIDE + d_own] = run; run += l2;
    offs[(w0+3) * OFFS_STRIDE + d_own] = run;
    __syncthreads();

    // (d) scatter: pure parallel writes — no ballots, no bump, no ordering.
    // addr = excl_base[w][d] + (pre + rank) == old leader-bump placement.
    #pragma unroll
    for (int q = 0; q < 32; q++){
      if (q < qmax){
        unsigned u = __float_as_uint(vreg[q]);
        unsigned key = ~(u ^ ((unsigned)(((int)u) >> 31) | 0x80000000u));
        unsigned d = (key >> sh) & 255u;
        unsigned lo = (lofs[q >> 1] >> ((q & 1) * 16)) & 0xFFFFu;
        row[offs[wbase + d] + lo] = vreg[q];
      }
    }
    __syncthreads();
  }

  // ---- phase 2: writeback sorted values + in-place p-transform ----
  {
    float4* b4 = (float4*)B;
    for (int i = tid; i < NVOC / 4; i += 1024){
      float4 v = *(const float4*)&row[i * 4];
      b4[i] = v;
      float4 p;
      p.x = expf(v.x - M) / Z;
      p.y = expf(v.y - M) / Z;
      p.z = expf(v.z - M) / Z;
      p.w = expf(v.w - M) / Z;
      *(float4*)&row[i * 4] = p;
    }
  }
  __syncthreads();   // p-values + global sorted row visible block-wide

  // ---- phase 3: lane-0 exact serial cumsum over full row (plain C++) ----
  if (tid == 0){
    float s = 0.f;
    int ks = NVOC - 1;
    for (int g = 0; g < NVOC / 32; g++){
      float prev = s;
      const float* p = &row[g * 32];
      #pragma unroll
      for (int q = 0; q < 32; q++) s += p[q];
      if (s > 0.9f){
        float t = prev;
        int kk = 31;
        for (int q = 0; q < 32; q++){
          t = t + p[q];                    // same values, same order
          if (t > 0.9f){ kk = q; break; }
        }
        ks = g * 32 + kk;
        break;
      }
    }
    float tv = B[ks];
    int jlo = ks;
    while (jlo > 0 && B[jlo - 1] == tv) jlo--;
    sh_tval = tv;
    sh_ckeep = ks + 1 - jlo;   // tokens equal to tv kept (stable index order)
  }
  __syncthreads();

  // ---- phase 4: gumbel-max over kept set ----
  float tval = sh_tval;
  int ckeep = sh_ckeep;
  float* redv = (float*)offs;              // 4 KB
  int*   redi = (int*)(offs + 1024);       // next 4 KB

  int stt = tid * 32;
  int en = min(stt + 32, NVOC);
  int eqc = 0;
  for (int i = stt; i < en; i++) eqc += (lrow[i] == tval) ? 1 : 0;
  int inc = eqc;
  #pragma unroll
  for (int dd = 1; dd < 64; dd <<= 1){
    int o = __shfl_up(inc, dd);
    if (lane >= dd) inc += o;
  }
  if (lane == 63) wtot[w] = inc;
  __syncthreads();
  int woff = 0;
  #pragma unroll
  for (int ww = 0; ww < 16; ww++) woff += (ww < w) ? wtot[ww] : 0;
  int eqrank = woff + inc - eqc;

  uint32_t fk0, fk1;
  threefry2x32(0u, 42u, 0u, (uint32_t)step, fk0, fk1);   // fold_in(key(42), step)
  float best = -INFINITY;
  int besti = NVOC;
  for (int i = stt; i < en; i++){
    float l = lrow[i];
    bool keep;
    if (l > tval) keep = true;
    else if (l == tval){ keep = (eqrank < ckeep); eqrank++; }
    else keep = false;
    if (keep){
      uint32_t o0, o1;
      threefry2x32(fk0, fk1, 0u, (uint32_t)(b * NVOC + i), o0, o1);
      uint32_t bits = o0 ^ o1;
      uint32_t fb2 = (bits >> 9) | 0x3f800000u;
      float u = __uint_as_float(fb2) - 1.0f;
      if (u == 0.0f) u = 1.17549435e-38f;   // minval = tiny
      float gum = -logf(-logf(u));
      float cand = l + gum;
      if (cand > best){ best = cand; besti = i; }
    }
  }
  redv[tid] = best;
  redi[tid] = besti;
  __syncthreads();
  for (int s = 512; s > 0; s >>= 1){
    if (tid < s){
      float ov = redv[tid + s]; int oi = redi[tid + s];
      if (ov > redv[tid] || (ov == redv[tid] && oi < redi[tid])){
        redv[tid] = ov; redi[tid] = oi;
      }
    }
    __syncthreads();
  }
  if (tid == 0) toks[(size_t)b * NSTEPS + step] = redi[0];
}

// ---------------- host launcher -------------------------------------------------
extern "C" void kernel_launch(void* const* d_in, const int* in_sizes, int n_in,
                              void* d_out, int out_size, void* d_ws, size_t ws_size,
                              hipStream_t stream)
{
  (void)in_sizes; (void)n_in; (void)out_size;
  const float* thought = (const float*)d_in[0];
  const float* vfeat   = (const float*)d_in[1];
  const float* emb     = (const float*)d_in[2];
  const float* w_ih0   = (const float*)d_in[3];
  const float* w_hh0   = (const float*)d_in[4];
  const float* b_ih0   = (const float*)d_in[5];
  const float* b_hh0   = (const float*)d_in[6];
  const float* w_ih1   = (const float*)d_in[7];
  const float* w_hh1   = (const float*)d_in[8];
  const float* b_ih1   = (const float*)d_in[9];
  const float* b_hh1   = (const float*)d_in[10];
  const float* gw1     = (const float*)d_in[11];
  const float* gb1     = (const float*)d_in[12];
  const float* gw2     = (const float*)d_in[13];
  const float* gb2     = (const float*)d_in[14];
  const float* out_w   = (const float*)d_in[15];
  const float* out_b   = (const float*)d_in[16];
  const float* vis_w   = (const float*)d_in[17];
  const float* vis_b   = (const float*)d_in[18];
  const float* ln_g    = (const float*)d_in[19];
  const float* ln_b    = (const float*)d_in[20];
  int* toks = (int*)d_out;

  char* ws = (char*)d_ws;
  size_t off = 0;
  auto alloc = [&](size_t bytes) -> void* {
    void* p = ws + off;
    off += (bytes + 255) & ~(size_t)255;
    return p;
  };
  float* vp      = (float*)alloc((size_t)NB * NNV * NH * 4);
  float* h0a     = (float*)alloc((size_t)NH * NB * 4);
  float* h0b     = (float*)alloc((size_t)NH * NB * 4);
  float* c0a     = (float*)alloc((size_t)NH * NB * 4);
  float* c0b     = (float*)alloc((size_t)NH * NB * 4);
  float* h1a     = (float*)alloc((size_t)NH * NB * 4);
  float* h1b     = (float*)alloc((size_t)NH * NB * 4);
  float* c1a     = (float*)alloc((size_t)NH * NB * 4);
  float* c1b     = (float*)alloc((size_t)NH * NB * 4);
  float* o2t     = (float*)alloc((size_t)NH * NB * 4);
  float* logits  = (float*)alloc((size_t)NB * NVOC * 4);
  float* sortbuf = (float*)alloc((size_t)NB * SORTSTRIDE * 4);// sorted rows
  if (off > ws_size) return;  // insufficient scratch: fail loudly via wrong output

  k_visgemm<<<dim3(VTOK / 64, NH / 64), 256, 0, stream>>>(vfeat, vis_w, vis_b, vp);
  k_visln<<<VTOK, 256, 0, stream>>>(ln_g, ln_b, vp);
  k_init<<<(NH * NB + 255) / 256, 256, 0, stream>>>(thought, h0a, c0a, h1a, c1a);

  for (int step = 0; step < NSTEPS; step++){
    float *h0r, *h0w, *c0r, *c0w, *h1r, *h1w, *c1r, *c1w;
    if ((step & 1) == 0){
      h0r = h0a; h0w = h0b; c0r = c0a; c0w = c0b;
      h1r = h1a; h1w = h1b; c1r = c1a; c1w = c1b;
    } else {
      h0r = h0b; h0w = h0a; c0r = c0b; c0w = c0a;
      h1r = h1b; h1w = h1a; c1r = c1b; c1w = c1a;
    }
    k_lstm<NE><<<dim3(32, 4), 256, 0, stream>>>(
        w_ih0, w_hh0, b_ih0, b_hh0, emb, toks, step, h0r, c0r, h0w, c0w);
    k_lstm<NH><<<dim3(32, 4), 256, 0, stream>>>(
        w_ih1, w_hh1, b_ih1, b_hh1, h0w, toks, step, h1r, c1r, h1w, c1w);
    k_gateattn<<<NB, 256, 0, stream>>>(h1w, gw1, gb1, gw2, gb2, vp, o2t);
    k_logits<<<NVOC / 64, 256, 0, stream>>>(o2t, out_w, out_b, toks, step, logits);
    k_sample<<<NB, 1024, 0, stream>>>(logits, sortbuf, toks, step);
  }
}